// Round 7
// baseline (358.784 us; speedup 1.0000x reference)
//
#include <hip/hip_runtime.h>

typedef short bf16x8 __attribute__((ext_vector_type(8)));
typedef float f32x4 __attribute__((ext_vector_type(4)));

#define MFMA16(a, b, c) __builtin_amdgcn_mfma_f32_16x16x32_bf16((a), (b), (c), 0, 0, 0)

static constexpr int T_LEN = 512;
static constexpr int F_DIM = 64;
static constexpr int NB    = 4;    // batch rows per block -> 1024 blocks -> 4 blocks/CU
static constexpr float C1  = 2.885390081777927f;  // 2*log2(e)

// exact RNE (one-time weight conversion only)
__device__ __forceinline__ unsigned short brne(float f) {
  unsigned u = __float_as_uint(f);
  return (unsigned short)((u + 0x7fffu + ((u >> 16) & 1u)) >> 16);
}

// v_cvt_pk_bf16_f32: packs 2 fp32 -> 2 bf16 (RNE) in one dword. No builtin.
__device__ __forceinline__ int cvtpk(float lo, float hi) {
  int r;
  asm("v_cvt_pk_bf16_f32 %0, %1, %2" : "=v"(r) : "v"(lo), "v"(hi));
  return r;
}

__device__ __forceinline__ bf16x8 cvt8(const float4 &a, const float4 &b) {
  typedef int int4v __attribute__((ext_vector_type(4)));
  int4v d = {cvtpk(a.x, a.y), cvtpk(a.z, a.w), cvtpk(b.x, b.y), cvtpk(b.z, b.w)};
  union { int4v i; bf16x8 h; } u;
  u.i = d;
  return u.h;
}

// DPP quad_perm(1,0,3,2): fetch xor-1 lane neighbor (all lanes active)
__device__ __forceinline__ float xor1(float v) {
  return __int_as_float(__builtin_amdgcn_mov_dpp(__float_as_int(v), 0xB1, 0xF, 0xF, true));
}

// tanh(s + bias) with bias pre-folded: c2 = C1*bias
__device__ __forceinline__ float tanh_fold(float s, float c2) {
  float e  = __builtin_amdgcn_exp2f(__builtin_fmaf(s, C1, c2));
  float rc = __builtin_amdgcn_rcpf(e + 1.0f);
  return __builtin_fmaf(-2.0f, rc, 1.0f);
}

// Redistribute one col-tile's 64 valid pre-acts (4 batch rows x 16 cols,
// resident as 4 regs of the g0 lanes at PAR=0 / g1 lanes at PAR=1) to one
// value per lane: lane L -> (batch row = L>>4, col = L&15).
// Uses the validated pl32 semantics (r[0]={a.lo32,b.lo32}) and the analogous
// pl16: r[0]={a.r0,b.r0,a.r2,b.r2}, r[1]={a.r1,b.r1,a.r3,b.r3} (16-lane rows).
template<int PAR>
__device__ __forceinline__ float redist(const f32x4 &a0, const f32x4 &a1) {
  int z0 = __float_as_int(a0[0] + a1[0]);
  int z1 = __float_as_int(a0[1] + a1[1]);
  int z2 = __float_as_int(a0[2] + a1[2]);
  int z3 = __float_as_int(a0[3] + a1[3]);
  auto r01 = __builtin_amdgcn_permlane16_swap(z0, z1, false, false);
  auto r23 = __builtin_amdgcn_permlane16_swap(z2, z3, false, false);
  int lo = (PAR == 0) ? r01[0] : r01[1];
  int hi = (PAR == 0) ? r23[0] : r23[1];
  auto f = __builtin_amdgcn_permlane32_swap(lo, hi, false, false);
  return __int_as_float(f[0]);
}

// One RNN step (m-cell then p-cell).  Wave owns 32 cols (2 col-tiles), block
// owns 4 batch rows.  PAR=0: valid C rows 0-3 (even-t x in A rows 0-3);
// PAR=1: valid C rows 4-7 (odd-t x in A rows 4-7).  A rows 8-15 duplicates.
template<int PAR, bool FIN>
__device__ __forceinline__ void step_cells(
    int arow, int g8, int wofsA, int rowF, int jA, bool evn,
    const bf16x8 &x0, const bf16x8 &x1,
    const bf16x8 (&Bm)[2][6], const bf16x8 (&Bp)[2][6],
    const float (&c2m)[2], const float (&c2p)[2], const f32x4 &Z,
    unsigned short (*sm_c)[72], unsigned short (*sm_p)[72],
    unsigned short (*sp_c)[72], unsigned short (*sp_p)[72],
    float (*mfin)[68], float (*pfin)[68])
{
  // p_old fragments (used by both cells; buffer not rewritten this step)
  bf16x8 p0 = *(const bf16x8 *)&sp_p[arow][g8];
  bf16x8 p1 = *(const bf16x8 *)&sp_p[arow][32 + g8];

  // ---------------- metrics cell: in = [x | p_old | m_old]
  {
    bf16x8 m0 = *(const bf16x8 *)&sm_p[arow][g8];
    bf16x8 m1 = *(const bf16x8 *)&sm_p[arow][32 + g8];
    f32x4 a00 = MFMA16(x0, Bm[0][0], Z);
    f32x4 a01 = MFMA16(x1, Bm[0][1], Z);
    f32x4 a10 = MFMA16(x0, Bm[1][0], Z);
    f32x4 a11 = MFMA16(x1, Bm[1][1], Z);
    a00 = MFMA16(p0, Bm[0][2], a00);
    a01 = MFMA16(p1, Bm[0][3], a01);
    a10 = MFMA16(p0, Bm[1][2], a10);
    a11 = MFMA16(p1, Bm[1][3], a11);
    a00 = MFMA16(m0, Bm[0][4], a00);
    a01 = MFMA16(m1, Bm[0][5], a01);
    a10 = MFMA16(m0, Bm[1][4], a10);
    a11 = MFMA16(m1, Bm[1][5], a11);
    float tA = tanh_fold(redist<PAR>(a00, a01), c2m[0]);
    float tB = tanh_fold(redist<PAR>(a10, a11), c2m[1]);
    float nA = xor1(tA);
    float nB = xor1(tB);
    if (evn) {
      unsigned short *p = &sm_c[0][0];
      *(unsigned *)(p + wofsA)      = (unsigned)cvtpk(tA, nA);
      *(unsigned *)(p + wofsA + 16) = (unsigned)cvtpk(tB, nB);
    }
    if (FIN) { mfin[rowF][jA] = tA; mfin[rowF][jA + 16] = tB; }
  }
  __syncthreads();   // m_new visible to both waves
  // ---------------- price cell: in = [x | m_new | p_old]; n-MFMAs last
  {
    bf16x8 n0 = *(const bf16x8 *)&sm_c[arow][g8];
    bf16x8 n1 = *(const bf16x8 *)&sm_c[arow][32 + g8];
    f32x4 a00 = MFMA16(x0, Bp[0][0], Z);
    f32x4 a01 = MFMA16(x1, Bp[0][1], Z);
    f32x4 a10 = MFMA16(x0, Bp[1][0], Z);
    f32x4 a11 = MFMA16(x1, Bp[1][1], Z);
    a00 = MFMA16(p0, Bp[0][4], a00);
    a01 = MFMA16(p1, Bp[0][5], a01);
    a10 = MFMA16(p0, Bp[1][4], a10);
    a11 = MFMA16(p1, Bp[1][5], a11);
    a00 = MFMA16(n0, Bp[0][2], a00);
    a01 = MFMA16(n1, Bp[0][3], a01);
    a10 = MFMA16(n0, Bp[1][2], a10);
    a11 = MFMA16(n1, Bp[1][3], a11);
    float tA = tanh_fold(redist<PAR>(a00, a01), c2p[0]);
    float tB = tanh_fold(redist<PAR>(a10, a11), c2p[1]);
    float nA = xor1(tA);
    float nB = xor1(tB);
    if (evn) {
      unsigned short *p = &sp_c[0][0];
      *(unsigned *)(p + wofsA)      = (unsigned)cvtpk(tA, nA);
      *(unsigned *)(p + wofsA + 16) = (unsigned)cvtpk(tB, nB);
    }
    if (FIN) { pfin[rowF][jA] = tA; pfin[rowF][jA + 16] = tB; }
  }
  __syncthreads();   // p_new visible; prev buffers free next step
}

__global__ __launch_bounds__(128, 2)
void mr_rnn_kernel(const float *__restrict__ x,
                   const float *__restrict__ mWih, const float *__restrict__ mWhh,
                   const float *__restrict__ mbih, const float *__restrict__ mbhh,
                   const float *__restrict__ pWih, const float *__restrict__ pWhh,
                   const float *__restrict__ pbih, const float *__restrict__ pbhh,
                   const float *__restrict__ plW,  const float *__restrict__ plb,
                   const float *__restrict__ mlW,  const float *__restrict__ mlb,
                   float *__restrict__ out, int B)
{
  __shared__ __align__(16) unsigned short sm[2][NB][72], sp[2][NB][72];
  __shared__ __align__(16) float s_mfin[NB][68], s_pfin[NB][68];

  const int tid  = threadIdx.x;
  const int lane = tid & 63;
  const int w    = tid >> 6;        // wave id 0/1 -> cols [32w, 32w+32)
  const int l15  = lane & 15;
  const int arow = l15 & (NB - 1);  // batch row within block
  const int half = (l15 >> 2) & 1;  // 0: carries x for even t, 1: for odd t
  const int g8   = (lane >> 4) * 8; // k-subgroup within a 32-K tile
  const int rowF = lane >> 4;       // batch row after redistribution
  const int b0   = blockIdx.x * NB;
  const int jA   = w * 32 + l15;    // first owned col (second = jA+16)
  const bool evn = (l15 & 1) == 0;
  const int wofsA = rowF * 72 + w * 32 + (l15 & ~1);  // packed write, shorts

  // ---- register-resident bf16 weight B-fragments: B[ct][kt][j] = W[j][k]
  bf16x8 Bm[2][6], Bp[2][6];
  float c2m[2], c2p[2];
#pragma unroll
  for (int ct = 0; ct < 2; ++ct) {
    const int j = w * 32 + ct * 16 + l15;
#pragma unroll
    for (int kt = 0; kt < 6; ++kt) {
      const int k0 = kt * 32 + g8;
#pragma unroll
      for (int i = 0; i < 8; ++i) {
        const int k = k0 + i;
        float wm = (k < 128) ? mWih[j * 128 + k] : mWhh[j * 64 + (k - 128)];
        float wp = (k < 128) ? pWih[j * 128 + k] : pWhh[j * 64 + (k - 128)];
        Bm[ct][kt][i] = (short)brne(wm);
        Bp[ct][kt][i] = (short)brne(wp);
      }
    }
    c2m[ct] = C1 * (mbih[j] + mbhh[j]);
    c2p[ct] = C1 * (pbih[j] + pbhh[j]);
  }
  const f32x4 Z = {0.f, 0.f, 0.f, 0.f};

  // ---- zero the t=-1 state buffers (parity index 1)
  for (int idx = tid; idx < NB * 72; idx += 128) {
    const int bb = idx / 72, kk = idx % 72;
    sm[1][bb][kk] = 0;
    sp[1][bb][kk] = 0;
  }

  // ---- x stream: lane covers batch b0+arow, step-parity `half`,
  //      features [g8,g8+8) and [32+g8,32+g8+8); pointer-bump addressing
  const float *pxl = x + ((size_t)(b0 + arow) * T_LEN + half) * F_DIM + g8;
  float4 A0 = *(const float4 *)(pxl);
  float4 A1 = *(const float4 *)(pxl + 4);
  float4 A2 = *(const float4 *)(pxl + 32);
  float4 A3 = *(const float4 *)(pxl + 36);
  bf16x8 x0 = cvt8(A0, A1);
  bf16x8 x1 = cvt8(A2, A3);
  __syncthreads();   // zero-init visible

#pragma unroll 1
  for (int t = 0; t < T_LEN - 2; t += 2) {
    // prefetch this lane's next x (step t+2+half)
    pxl += 2 * F_DIM;
    A0 = *(const float4 *)(pxl);
    A1 = *(const float4 *)(pxl + 4);
    A2 = *(const float4 *)(pxl + 32);
    A3 = *(const float4 *)(pxl + 36);
    // step t (even): cur parity 0, prev 1
    step_cells<0, false>(arow, g8, wofsA, rowF, jA, evn, x0, x1, Bm, Bp,
                         c2m, c2p, Z,
                         sm[0], sm[1], sp[0], sp[1], s_mfin, s_pfin);
    // step t+1 (odd): cur parity 1, prev 0 — same x frags, other rows valid
    step_cells<1, false>(arow, g8, wofsA, rowF, jA, evn, x0, x1, Bm, Bp,
                         c2m, c2p, Z,
                         sm[1], sm[0], sp[1], sp[0], s_mfin, s_pfin);
    x0 = cvt8(A0, A1);
    x1 = cvt8(A2, A3);
  }
  // ---- steps 510, 511 (no prefetch; 511 writes fp32 finals)
  step_cells<0, false>(arow, g8, wofsA, rowF, jA, evn, x0, x1, Bm, Bp,
                       c2m, c2p, Z,
                       sm[0], sm[1], sp[0], sp[1], s_mfin, s_pfin);
  step_cells<1, true>(arow, g8, wofsA, rowF, jA, evn, x0, x1, Bm, Bp,
                      c2m, c2p, Z,
                      sm[1], sm[0], sp[1], sp[0], s_mfin, s_pfin);

  // ---- heads (trailing __syncthreads inside step_cells orders s_*fin)
  if (tid < NB) {
    const int b = tid;
    float acc = plb[0];
#pragma unroll 1
    for (int k = 0; k < 64; ++k) acc += s_pfin[b][k] * plW[k];
    out[b0 + b] = acc;
  } else if (tid < NB + NB * 8) {
    const int r = tid - NB;
    const int b = r >> 3, e = r & 7;
    float acc = mlb[e];
#pragma unroll 1
    for (int k = 0; k < 64; ++k) acc += s_mfin[b][k] * mlW[e * 64 + k];
    out[(size_t)B + (size_t)(b0 + b) * 8 + e] = acc;
  }
}

extern "C" void kernel_launch(void* const* d_in, const int* in_sizes, int n_in,
                              void* d_out, int out_size, void* d_ws, size_t ws_size,
                              hipStream_t stream) {
  (void)n_in; (void)out_size; (void)d_ws; (void)ws_size;
  const float* x    = (const float*)d_in[0];
  const float* mWih = (const float*)d_in[1];
  const float* mWhh = (const float*)d_in[2];
  const float* mbih = (const float*)d_in[3];
  const float* mbhh = (const float*)d_in[4];
  const float* pWih = (const float*)d_in[5];
  const float* pWhh = (const float*)d_in[6];
  const float* pbih = (const float*)d_in[7];
  const float* pbhh = (const float*)d_in[8];
  const float* plW  = (const float*)d_in[9];
  const float* plb  = (const float*)d_in[10];
  const float* mlW  = (const float*)d_in[11];
  const float* mlb  = (const float*)d_in[12];
  const int B = in_sizes[0] / (T_LEN * F_DIM);
  const int nblk = B / NB;   // 1024 blocks -> 4 independent blocks/CU
  mr_rnn_kernel<<<dim3(nblk), dim3(128), 0, stream>>>(
      x, mWih, mWhh, mbih, mbhh, pWih, pWhh, pbih, pbhh,
      plW, plb, mlW, mlb, (float*)d_out, B);
}

// Round 8
// 292.020 us; speedup vs baseline: 1.2286x; 1.2286x over previous
//
#include <hip/hip_runtime.h>

typedef short bf16x8 __attribute__((ext_vector_type(8)));
typedef float f32x4 __attribute__((ext_vector_type(4)));
typedef int   int4v  __attribute__((ext_vector_type(4)));

#define MFMA16(a, b, c) __builtin_amdgcn_mfma_f32_16x16x32_bf16((a), (b), (c), 0, 0, 0)

static constexpr int T_LEN = 512;
static constexpr int F_DIM = 64;
static constexpr int NB    = 8;    // batch rows per block -> 512 blocks -> 2 blocks/CU
static constexpr float C1  = 2.885390081777927f;  // 2*log2(e)

// exact RNE (one-time weight conversion only)
__device__ __forceinline__ unsigned short brne(float f) {
  unsigned u = __float_as_uint(f);
  return (unsigned short)((u + 0x7fffu + ((u >> 16) & 1u)) >> 16);
}

// v_cvt_pk_bf16_f32: packs 2 fp32 -> 2 bf16 (RNE) in one dword. No builtin.
__device__ __forceinline__ int cvtpk(float lo, float hi) {
  int r;
  asm("v_cvt_pk_bf16_f32 %0, %1, %2" : "=v"(r) : "v"(lo), "v"(hi));
  return r;
}

__device__ __forceinline__ bf16x8 cvt8(const float4 &a, const float4 &b) {
  int4v d = {cvtpk(a.x, a.y), cvtpk(a.z, a.w), cvtpk(b.x, b.y), cvtpk(b.z, b.w)};
  union { int4v i; bf16x8 h; } u;
  u.i = d;
  return u.h;
}

// v_permlane32_swap_b32: r[0] = {a[0:31], b[0:31]}, r[1] = {a[32:63], b[32:63]}
__device__ __forceinline__ void swap32(float &a, float &b) {
  auto r = __builtin_amdgcn_permlane32_swap(__float_as_int(a), __float_as_int(b),
                                            false, false);
  a = __int_as_float(r[0]);
  b = __int_as_float(r[1]);
}

// DPP quad_perm(1,0,3,2): fetch xor-1 lane neighbor (all lanes active)
__device__ __forceinline__ float xor1(float v) {
  return __int_as_float(__builtin_amdgcn_mov_dpp(__float_as_int(v), 0xB1, 0xF, 0xF, true));
}

// tanh(s + bias) with bias pre-folded: c2 = C1*bias
__device__ __forceinline__ float tanh_fold(float s, float c2) {
  float e  = __builtin_amdgcn_exp2f(__builtin_fmaf(s, C1, c2));
  float rc = __builtin_amdgcn_rcpf(e + 1.0f);
  return __builtin_fmaf(-2.0f, rc, 1.0f);
}

// Raw workgroup barrier: orders LDS (lgkmcnt) but leaves global prefetch
// loads (vmcnt) in flight — __syncthreads would drain vmcnt(0) every step
// and serialize the x-prefetch latency into the chain.
__device__ __forceinline__ void bar() {
  asm volatile("s_waitcnt lgkmcnt(0)" ::: "memory");
  __builtin_amdgcn_s_barrier();
  __builtin_amdgcn_sched_barrier(0);  // keep post-barrier LDS reads below
}

// Epilogue: redistribute 8 half-exec pre-acts to 2 full-exec values, tanh,
// pack pairs along j, write packed b32s.  wofs/evn/rowA precomputed.
template<int PAR, bool FIN>
__device__ __forceinline__ void epilogue(
    const f32x4 &a0, const f32x4 &a1, float c2,
    unsigned short (*buf)[72], float (*fin)[68],
    int wofs, bool evn, int rowA, int j)
{
  float z0 = a0[0] + a1[0];
  float z1 = a0[1] + a1[1];
  float z2 = a0[2] + a1[2];
  float z3 = a0[3] + a1[3];
  swap32(z0, z2);            // z0={z0.lo,z2.lo}, z2={z0.hi,z2.hi}
  swap32(z1, z3);
  float sA = (PAR == 0) ? z0 : z2;
  float sB = (PAR == 0) ? z1 : z3;
  float tA = tanh_fold(sA, c2);
  float tB = tanh_fold(sB, c2);
  float nA = xor1(tA);
  float nB = xor1(tB);
  if (evn) {                 // even-j lanes write packed (j, j+1) dwords
    unsigned short *p = &buf[0][0];
    *(unsigned *)(p + wofs)      = (unsigned)cvtpk(tA, nA);
    *(unsigned *)(p + wofs + 72) = (unsigned)cvtpk(tB, nB);
  }
  if (FIN) {                 // fp32 finals (rows rowA, rowA+1 at col j)
    fin[rowA][j]     = tA;
    fin[rowA + 1][j] = tB;
  }
}

// One RNN step (m-cell then p-cell).  PAR=0 (even t): valid C rows 0-7 end up
// in lanes 0-31 after redistribution.  PAR=1: lanes 32-63 source.
// p-cell's x/p_old MFMAs are hoisted ABOVE barrier 1 (independent of m_new)
// so their issue fills the m-epilogue's transcendental latency window.
template<int PAR, bool FIN>
__device__ __forceinline__ void step_cells(
    int arow, int g8, int j, int wofs, bool evn, int rowA,
    const bf16x8 &x0, const bf16x8 &x1,
    const bf16x8 (&Bm)[6], const bf16x8 (&Bp)[6],
    float c2m, float c2p, const f32x4 &Z,
    unsigned short (*sm_c)[72], unsigned short (*sm_p)[72],
    unsigned short (*sp_c)[72], unsigned short (*sp_p)[72],
    float (*mfin)[68], float (*pfin)[68])
{
  // state fragments (issued early; latency covered by x-MFMAs)
  bf16x8 p0 = *(const bf16x8 *)&sp_p[arow][g8];
  bf16x8 p1 = *(const bf16x8 *)&sp_p[arow][32 + g8];
  bf16x8 m0 = *(const bf16x8 *)&sm_p[arow][g8];
  bf16x8 m1 = *(const bf16x8 *)&sm_p[arow][32 + g8];

  // ---------------- metrics cell: in = [x | p_old | m_old]
  f32x4 a0 = MFMA16(x0, Bm[0], Z);
  f32x4 a1 = MFMA16(x1, Bm[1], Z);
  a0 = MFMA16(p0, Bm[2], a0);
  a1 = MFMA16(p1, Bm[3], a1);
  a0 = MFMA16(m0, Bm[4], a0);
  a1 = MFMA16(m1, Bm[5], a1);
  // p-cell independent part (x, p_old) — hoisted above barrier 1
  f32x4 b0 = MFMA16(x0, Bp[0], Z);
  f32x4 b1 = MFMA16(x1, Bp[1], Z);
  b0 = MFMA16(p0, Bp[4], b0);
  b1 = MFMA16(p1, Bp[5], b1);
  epilogue<PAR, FIN>(a0, a1, c2m, sm_c, mfin, wofs, evn, rowA, j);
  bar();   // m_new visible to all waves
  // ---------------- price cell: m_new-dependent tail
  {
    bf16x8 n0 = *(const bf16x8 *)&sm_c[arow][g8];
    bf16x8 n1 = *(const bf16x8 *)&sm_c[arow][32 + g8];
    b0 = MFMA16(n0, Bp[2], b0);
    b1 = MFMA16(n1, Bp[3], b1);
    epilogue<PAR, FIN>(b0, b1, c2p, sp_c, pfin, wofs, evn, rowA, j);
  }
  bar();   // p_new visible; prev buffers free next step
}

__global__ __launch_bounds__(256, 2)
void mr_rnn_kernel(const float *__restrict__ x,
                   const float *__restrict__ mWih, const float *__restrict__ mWhh,
                   const float *__restrict__ mbih, const float *__restrict__ mbhh,
                   const float *__restrict__ pWih, const float *__restrict__ pWhh,
                   const float *__restrict__ pbih, const float *__restrict__ pbhh,
                   const float *__restrict__ plW,  const float *__restrict__ plb,
                   const float *__restrict__ mlW,  const float *__restrict__ mlb,
                   float *__restrict__ out, int B)
{
  __shared__ __align__(16) unsigned short sm[2][NB][72], sp[2][NB][72];
  __shared__ __align__(16) float s_mfin[NB][68], s_pfin[NB][68];

  const int tid  = threadIdx.x;
  const int lane = tid & 63;
  const int q    = tid >> 6;        // wave id -> output col tile
  const int l15  = lane & 15;
  const int arow = l15 & (NB - 1);  // batch row within block
  const int half = l15 >> 3;        // 0: carries x for even t, 1: for odd t
  const int g    = lane >> 4;       // k-group
  const int j    = q * 16 + l15;    // output feature owned by this lane's wave
  const int b0   = blockIdx.x * NB;
  const int g8   = g * 8;
  // epilogue lane constants: rows (rowA, rowA+1), packed write offset (shorts)
  const int rowA = ((lane & 16) >> 2) | ((lane >> 5) << 1);  // 4*gb + 2*(lane>=32)
  const bool evn = (l15 & 1) == 0;
  const int wofs = rowA * 72 + (j & ~1);

  // ---- register-resident bf16 weight B-fragments: B[k][j] = W[j][k]
  bf16x8 Bm[6], Bp[6];
#pragma unroll
  for (int kt = 0; kt < 6; ++kt) {
    const int k0 = kt * 32 + g8;
#pragma unroll
    for (int i = 0; i < 8; ++i) {
      const int k = k0 + i;
      float wm = (k < 128) ? mWih[j * 128 + k] : mWhh[j * 64 + (k - 128)];
      float wp = (k < 128) ? pWih[j * 128 + k] : pWhh[j * 64 + (k - 128)];
      Bm[kt][i] = (short)brne(wm);
      Bp[kt][i] = (short)brne(wp);
    }
  }
  const float c2m = C1 * (mbih[j] + mbhh[j]);   // bias folded into exp2 arg
  const float c2p = C1 * (pbih[j] + pbhh[j]);
  const f32x4 Z = {0.f, 0.f, 0.f, 0.f};         // hoisted accumulator seed

  // ---- zero the t=-1 state buffers (parity index 1)
  for (int idx = tid; idx < NB * 72; idx += 256) {
    const int bb = idx / 72, kk = idx % 72;
    sm[1][bb][kk] = 0;
    sp[1][bb][kk] = 0;
  }

  // ---- x stream: lane covers batch b0+arow, step-parity `half`,
  //      features [g8,g8+8) and [32+g8,32+g8+8); pointer-bump addressing
  const float *pxl = x + ((size_t)(b0 + arow) * T_LEN + half) * F_DIM + g8;
  float4 A0 = *(const float4 *)(pxl);
  float4 A1 = *(const float4 *)(pxl + 4);
  float4 A2 = *(const float4 *)(pxl + 32);
  float4 A3 = *(const float4 *)(pxl + 36);
  bf16x8 x0 = cvt8(A0, A1);
  bf16x8 x1 = cvt8(A2, A3);
  __syncthreads();   // zero-init visible (one full drain, outside the loop)

#pragma unroll 1
  for (int t = 0; t < T_LEN - 2; t += 2) {
    // prefetch this lane's next x (step t+2+half); stays in flight across
    // the raw barriers (no vmcnt drain), consumed at loop bottom
    pxl += 2 * F_DIM;
    A0 = *(const float4 *)(pxl);
    A1 = *(const float4 *)(pxl + 4);
    A2 = *(const float4 *)(pxl + 32);
    A3 = *(const float4 *)(pxl + 36);
    // step t (even): cur parity 0, prev 1
    step_cells<0, false>(arow, g8, j, wofs, evn, rowA, x0, x1, Bm, Bp, c2m, c2p, Z,
                         sm[0], sm[1], sp[0], sp[1], s_mfin, s_pfin);
    // step t+1 (odd): cur parity 1, prev 0 — same x frags, other half valid
    step_cells<1, false>(arow, g8, j, wofs, evn, rowA, x0, x1, Bm, Bp, c2m, c2p, Z,
                         sm[1], sm[0], sp[1], sp[0], s_mfin, s_pfin);
    x0 = cvt8(A0, A1);
    x1 = cvt8(A2, A3);
  }
  // ---- steps 510, 511 (no prefetch; 511 writes fp32 finals)
  step_cells<0, false>(arow, g8, j, wofs, evn, rowA, x0, x1, Bm, Bp, c2m, c2p, Z,
                       sm[0], sm[1], sp[0], sp[1], s_mfin, s_pfin);
  step_cells<1, true>(arow, g8, j, wofs, evn, rowA, x0, x1, Bm, Bp, c2m, c2p, Z,
                      sm[1], sm[0], sp[1], sp[0], s_mfin, s_pfin);

  // ---- heads (trailing bar() inside step_cells orders s_*fin)
  if (tid < NB) {
    const int b = tid;
    float acc = plb[0];
#pragma unroll 1
    for (int k = 0; k < 64; ++k) acc += s_pfin[b][k] * plW[k];
    out[b0 + b] = acc;
  } else if (tid < NB + NB * 8) {
    const int r = tid - NB;
    const int b = r >> 3, e = r & 7;
    float acc = mlb[e];
#pragma unroll 1
    for (int k = 0; k < 64; ++k) acc += s_mfin[b][k] * mlW[e * 64 + k];
    out[(size_t)B + (size_t)(b0 + b) * 8 + e] = acc;
  }
}

extern "C" void kernel_launch(void* const* d_in, const int* in_sizes, int n_in,
                              void* d_out, int out_size, void* d_ws, size_t ws_size,
                              hipStream_t stream) {
  (void)n_in; (void)out_size; (void)d_ws; (void)ws_size;
  const float* x    = (const float*)d_in[0];
  const float* mWih = (const float*)d_in[1];
  const float* mWhh = (const float*)d_in[2];
  const float* mbih = (const float*)d_in[3];
  const float* mbhh = (const float*)d_in[4];
  const float* pWih = (const float*)d_in[5];
  const float* pWhh = (const float*)d_in[6];
  const float* pbih = (const float*)d_in[7];
  const float* pbhh = (const float*)d_in[8];
  const float* plW  = (const float*)d_in[9];
  const float* plb  = (const float*)d_in[10];
  const float* mlW  = (const float*)d_in[11];
  const float* mlb  = (const float*)d_in[12];
  const int B = in_sizes[0] / (T_LEN * F_DIM);
  const int nblk = B / NB;   // 512 blocks -> 2 blocks/CU -> 2 waves/SIMD
  mr_rnn_kernel<<<dim3(nblk), dim3(256), 0, stream>>>(
      x, mWih, mWhh, mbih, mbhh, pWih, pWhh, pbih, pbhh,
      plW, plb, mlW, mlb, (float*)d_out, B);
}

// Round 12
// 270.328 us; speedup vs baseline: 1.3272x; 1.0802x over previous
//
#include <hip/hip_runtime.h>

typedef short bf16x8 __attribute__((ext_vector_type(8)));
typedef float f32x4 __attribute__((ext_vector_type(4)));
typedef int   int4v  __attribute__((ext_vector_type(4)));

#define MFMA16(a, b, c) __builtin_amdgcn_mfma_f32_16x16x32_bf16((a), (b), (c), 0, 0, 0)

static constexpr int T_LEN = 512;
static constexpr int F_DIM = 64;
static constexpr int NB    = 8;    // batch rows per block -> 512 blocks -> 2 blocks/CU
static constexpr float C1  = 2.885390081777927f;  // 2*log2(e)

// exact RNE (one-time weight conversion only)
__device__ __forceinline__ unsigned short brne(float f) {
  unsigned u = __float_as_uint(f);
  return (unsigned short)((u + 0x7fffu + ((u >> 16) & 1u)) >> 16);
}

// v_cvt_pk_bf16_f32: packs 2 fp32 -> 2 bf16 (RNE) in one dword. No builtin.
__device__ __forceinline__ int cvtpk(float lo, float hi) {
  int r;
  asm("v_cvt_pk_bf16_f32 %0, %1, %2" : "=v"(r) : "v"(lo), "v"(hi));
  return r;
}

__device__ __forceinline__ bf16x8 cvt8(const float4 &a, const float4 &b) {
  int4v d = {cvtpk(a.x, a.y), cvtpk(a.z, a.w), cvtpk(b.x, b.y), cvtpk(b.z, b.w)};
  union { int4v i; bf16x8 h; } u;
  u.i = d;
  return u.h;
}

// v_permlane32_swap_b32: r[0] = {a[0:31], b[0:31]}, r[1] = {a[32:63], b[32:63]}
__device__ __forceinline__ void swap32(float &a, float &b) {
  auto r = __builtin_amdgcn_permlane32_swap(__float_as_int(a), __float_as_int(b),
                                            false, false);
  a = __int_as_float(r[0]);
  b = __int_as_float(r[1]);
}

// DPP quad_perm(1,0,3,2): fetch xor-1 lane neighbor (all lanes active)
__device__ __forceinline__ float xor1(float v) {
  return __int_as_float(__builtin_amdgcn_mov_dpp(__float_as_int(v), 0xB1, 0xF, 0xF, true));
}

// tanh(s + bias) with bias pre-folded: c2 = C1*bias
__device__ __forceinline__ float tanh_fold(float s, float c2) {
  float e  = __builtin_amdgcn_exp2f(__builtin_fmaf(s, C1, c2));
  float rc = __builtin_amdgcn_rcpf(e + 1.0f);
  return __builtin_fmaf(-2.0f, rc, 1.0f);
}

// Epilogue: redistribute 8 half-exec pre-acts to 2 full-exec values, tanh,
// pack pairs along j, write packed b32s.  wofs/evn/rowA precomputed.
template<int PAR, bool FIN>
__device__ __forceinline__ void epilogue(
    const f32x4 &a0, const f32x4 &a1, float c2,
    unsigned short (*buf)[72], float (*fin)[68],
    int wofs, bool evn, int rowA, int j)
{
  float z0 = a0[0] + a1[0];
  float z1 = a0[1] + a1[1];
  float z2 = a0[2] + a1[2];
  float z3 = a0[3] + a1[3];
  swap32(z0, z2);            // z0={z0.lo,z2.lo}, z2={z0.hi,z2.hi}
  swap32(z1, z3);
  float sA = (PAR == 0) ? z0 : z2;
  float sB = (PAR == 0) ? z1 : z3;
  float tA = tanh_fold(sA, c2);
  float tB = tanh_fold(sB, c2);
  float nA = xor1(tA);
  float nB = xor1(tB);
  if (evn) {                 // even-j lanes write packed (j, j+1) dwords
    unsigned short *p = &buf[0][0];
    *(unsigned *)(p + wofs)      = (unsigned)cvtpk(tA, nA);
    *(unsigned *)(p + wofs + 72) = (unsigned)cvtpk(tB, nB);
  }
  if (FIN) {                 // fp32 finals (rows rowA, rowA+1 at col j)
    fin[rowA][j]     = tA;
    fin[rowA + 1][j] = tB;
  }
}

// One RNN step (m-cell then p-cell), round-6 validated structure.
// PAR=0 (even t): valid C rows 0-7 sourced from lanes 0-31.  PAR=1: 32-63.
// m_old A-frags (mo0/mo1) are CARRIED IN REGISTERS: the p-cell reads m(t) as
// n0/n1 and hands them to the next step's m-cell (identical values the m-cell
// would re-read from LDS) — saves 2 ds_read_b128/step and makes 4 of the
// m-cell's 6 MFMAs LDS-independent right after the barrier.  Bit-identical
// arithmetic vs round 6 (same values, same MFMA order).
template<int PAR, bool FIN>
__device__ __forceinline__ void step_cells(
    int arow, int g8, int j, int wofs, bool evn, int rowA,
    const bf16x8 &x0, const bf16x8 &x1,
    bf16x8 &mo0, bf16x8 &mo1,
    const bf16x8 (&Bm)[6], const bf16x8 (&Bp)[6],
    float c2m, float c2p, const f32x4 &Z,
    unsigned short (*sm)[72],
    unsigned short (*sp_c)[72], unsigned short (*sp_p)[72],
    float (*mfin)[68], float (*pfin)[68])
{
  // p_old fragments (written before last step's trailing barrier; reused by
  // both cells; buffer not rewritten this step)
  bf16x8 p0 = *(const bf16x8 *)&sp_p[arow][g8];
  bf16x8 p1 = *(const bf16x8 *)&sp_p[arow][32 + g8];

  // ---------------- metrics cell: in = [x | p_old | m_old(carried)]
  __builtin_amdgcn_s_setprio(1);       // favor the serial chain over the
  {                                    // co-resident block's idle waves
    f32x4 a0 = MFMA16(x0, Bm[0], Z);
    f32x4 a1 = MFMA16(x1, Bm[1], Z);
    a0 = MFMA16(p0, Bm[2], a0);
    a1 = MFMA16(p1, Bm[3], a1);
    a0 = MFMA16(mo0, Bm[4], a0);
    a1 = MFMA16(mo1, Bm[5], a1);
    epilogue<PAR, FIN>(a0, a1, c2m, sm, mfin, wofs, evn, rowA, j);
  }
  __builtin_amdgcn_s_setprio(0);
  __syncthreads();   // m_new visible to all waves
  // ---------------- price cell: in = [x | m_new | p_old]
  {
    bf16x8 n0 = *(const bf16x8 *)&sm[arow][g8];
    bf16x8 n1 = *(const bf16x8 *)&sm[arow][32 + g8];
    __builtin_amdgcn_s_setprio(1);
    f32x4 b0 = MFMA16(x0, Bp[0], Z);
    f32x4 b1 = MFMA16(x1, Bp[1], Z);
    b0 = MFMA16(n0, Bp[2], b0);
    b1 = MFMA16(n1, Bp[3], b1);
    b0 = MFMA16(p0, Bp[4], b0);
    b1 = MFMA16(p1, Bp[5], b1);
    epilogue<PAR, FIN>(b0, b1, c2p, sp_c, pfin, wofs, evn, rowA, j);
    __builtin_amdgcn_s_setprio(0);
    mo0 = n0;   // carry m(t) -> next step's m_old (bit-identical to a re-read)
    mo1 = n1;
  }
  __syncthreads();   // p_new visible; prev p-buffer free next step
}

__global__ __launch_bounds__(256, 2)
void mr_rnn_kernel(const float *__restrict__ x,
                   const float *__restrict__ mWih, const float *__restrict__ mWhh,
                   const float *__restrict__ mbih, const float *__restrict__ mbhh,
                   const float *__restrict__ pWih, const float *__restrict__ pWhh,
                   const float *__restrict__ pbih, const float *__restrict__ pbhh,
                   const float *__restrict__ plW,  const float *__restrict__ plb,
                   const float *__restrict__ mlW,  const float *__restrict__ mlb,
                   float *__restrict__ out, int B)
{
  __shared__ __align__(16) unsigned short sm[NB][72];      // single m buffer
  __shared__ __align__(16) unsigned short sp[2][NB][72];   // p double buffer
  __shared__ __align__(16) float s_mfin[NB][68], s_pfin[NB][68];

  const int tid  = threadIdx.x;
  const int lane = tid & 63;
  const int q    = tid >> 6;        // wave id -> output col tile
  const int l15  = lane & 15;
  const int arow = l15 & (NB - 1);  // batch row within block
  const int half = l15 >> 3;        // 0: carries x for even t, 1: for odd t
  const int g    = lane >> 4;       // k-group
  const int j    = q * 16 + l15;    // output feature owned by this lane's wave
  const int b0   = blockIdx.x * NB;
  const int g8   = g * 8;
  // epilogue lane constants: rows (rowA, rowA+1), packed write offset (shorts)
  const int rowA = ((lane & 16) >> 2) | ((lane >> 5) << 1);  // 4*gb + 2*(lane>=32)
  const bool evn = (l15 & 1) == 0;
  const int wofs = rowA * 72 + (j & ~1);

  // ---- register-resident bf16 weight B-fragments: B[k][j] = W[j][k]
  bf16x8 Bm[6], Bp[6];
#pragma unroll
  for (int kt = 0; kt < 6; ++kt) {
    const int k0 = kt * 32 + g8;
#pragma unroll
    for (int i = 0; i < 8; ++i) {
      const int k = k0 + i;
      float wm = (k < 128) ? mWih[j * 128 + k] : mWhh[j * 64 + (k - 128)];
      float wp = (k < 128) ? pWih[j * 128 + k] : pWhh[j * 64 + (k - 128)];
      Bm[kt][i] = (short)brne(wm);
      Bp[kt][i] = (short)brne(wp);
    }
  }
  const float c2m = C1 * (mbih[j] + mbhh[j]);   // bias folded into exp2 arg
  const float c2p = C1 * (pbih[j] + pbhh[j]);
  const f32x4 Z = {0.f, 0.f, 0.f, 0.f};         // hoisted accumulator seed

  // ---- zero the t=-1 p-state buffer (parity index 1); m(-1)=0 is carried
  for (int idx = tid; idx < NB * 72; idx += 256) {
    const int bb = idx / 72, kk = idx % 72;
    sp[1][bb][kk] = 0;
  }
  bf16x8 mo0 = {0, 0, 0, 0, 0, 0, 0, 0};   // m(-1) = 0 (bf16 zero bits)
  bf16x8 mo1 = {0, 0, 0, 0, 0, 0, 0, 0};

  // ---- x stream: lane covers batch b0+arow, step-parity `half`,
  //      features [g8,g8+8) and [32+g8,32+g8+8); pointer-bump addressing
  const float *pxl = x + ((size_t)(b0 + arow) * T_LEN + half) * F_DIM + g8;
  float4 A0 = *(const float4 *)(pxl);
  float4 A1 = *(const float4 *)(pxl + 4);
  float4 A2 = *(const float4 *)(pxl + 32);
  float4 A3 = *(const float4 *)(pxl + 36);
  bf16x8 x0 = cvt8(A0, A1);
  bf16x8 x1 = cvt8(A2, A3);
  __syncthreads();   // zero-init visible

#pragma unroll 1
  for (int t = 0; t < T_LEN - 2; t += 2) {
    // prefetch this lane's next x (step t+2+half)
    pxl += 2 * F_DIM;
    A0 = *(const float4 *)(pxl);
    A1 = *(const float4 *)(pxl + 4);
    A2 = *(const float4 *)(pxl + 32);
    A3 = *(const float4 *)(pxl + 36);
    // step t (even): p cur parity 0, prev 1
    step_cells<0, false>(arow, g8, j, wofs, evn, rowA, x0, x1, mo0, mo1,
                         Bm, Bp, c2m, c2p, Z,
                         sm, sp[0], sp[1], s_mfin, s_pfin);
    // step t+1 (odd): p cur parity 1, prev 0 — same x frags, other half valid
    step_cells<1, false>(arow, g8, j, wofs, evn, rowA, x0, x1, mo0, mo1,
                         Bm, Bp, c2m, c2p, Z,
                         sm, sp[1], sp[0], s_mfin, s_pfin);
    x0 = cvt8(A0, A1);
    x1 = cvt8(A2, A3);
  }
  // ---- steps 510, 511 (no prefetch; 511 writes fp32 finals)
  step_cells<0, false>(arow, g8, j, wofs, evn, rowA, x0, x1, mo0, mo1,
                       Bm, Bp, c2m, c2p, Z,
                       sm, sp[0], sp[1], s_mfin, s_pfin);
  step_cells<1, true>(arow, g8, j, wofs, evn, rowA, x0, x1, mo0, mo1,
                      Bm, Bp, c2m, c2p, Z,
                      sm, sp[1], sp[0], s_mfin, s_pfin);

  // ---- heads (trailing __syncthreads inside step_cells orders s_*fin)
  if (tid < NB) {
    const int b = tid;
    float acc = plb[0];
#pragma unroll 1
    for (int k = 0; k < 64; ++k) acc += s_pfin[b][k] * plW[k];
    out[b0 + b] = acc;
  } else if (tid < NB + NB * 8) {
    const int r = tid - NB;
    const int b = r >> 3, e = r & 7;
    float acc = mlb[e];
#pragma unroll 1
    for (int k = 0; k < 64; ++k) acc += s_mfin[b][k] * mlW[e * 64 + k];
    out[(size_t)B + (size_t)(b0 + b) * 8 + e] = acc;
  }
}

extern "C" void kernel_launch(void* const* d_in, const int* in_sizes, int n_in,
                              void* d_out, int out_size, void* d_ws, size_t ws_size,
                              hipStream_t stream) {
  (void)n_in; (void)out_size; (void)d_ws; (void)ws_size;
  const float* x    = (const float*)d_in[0];
  const float* mWih = (const float*)d_in[1];
  const float* mWhh = (const float*)d_in[2];
  const float* mbih = (const float*)d_in[3];
  const float* mbhh = (const float*)d_in[4];
  const float* pWih = (const float*)d_in[5];
  const float* pWhh = (const float*)d_in[6];
  const float* pbih = (const float*)d_in[7];
  const float* pbhh = (const float*)d_in[8];
  const float* plW  = (const float*)d_in[9];
  const float* plb  = (const float*)d_in[10];
  const float* mlW  = (const float*)d_in[11];
  const float* mlb  = (const float*)d_in[12];
  const int B = in_sizes[0] / (T_LEN * F_DIM);
  const int nblk = B / NB;   // 512 blocks -> 2 blocks/CU -> 2 waves/SIMD
  mr_rnn_kernel<<<dim3(nblk), dim3(256), 0, stream>>>(
      x, mWih, mWhh, mbih, mbhh, pWih, pWhh, pbih, pbhh,
      plW, plb, mlW, mlb, (float*)d_out, B);
}

// Round 13
// 263.693 us; speedup vs baseline: 1.3606x; 1.0252x over previous
//
#include <hip/hip_runtime.h>

typedef short bf16x8 __attribute__((ext_vector_type(8)));
typedef float f32x4 __attribute__((ext_vector_type(4)));
typedef int   int4v  __attribute__((ext_vector_type(4)));

#define MFMA16(a, b, c) __builtin_amdgcn_mfma_f32_16x16x32_bf16((a), (b), (c), 0, 0, 0)

static constexpr int T_LEN = 512;
static constexpr int F_DIM = 64;
static constexpr int NB    = 16;   // batch rows per block -> 256 blocks -> 1 block/CU
static constexpr float C1  = 2.885390081777927f;  // 2*log2(e)

// exact RNE (one-time weight conversion only)
__device__ __forceinline__ unsigned short brne(float f) {
  unsigned u = __float_as_uint(f);
  return (unsigned short)((u + 0x7fffu + ((u >> 16) & 1u)) >> 16);
}

// round-half-up fp32->bf16 (2 VALU ops; validated rounds 4-12)
__device__ __forceinline__ unsigned short rhu(float f) {
  return (unsigned short)((__float_as_uint(f) + 0x8000u) >> 16);
}

// v_cvt_pk_bf16_f32: packs 2 fp32 -> 2 bf16 (RNE) in one dword. No builtin.
__device__ __forceinline__ int cvtpk(float lo, float hi) {
  int r;
  asm("v_cvt_pk_bf16_f32 %0, %1, %2" : "=v"(r) : "v"(lo), "v"(hi));
  return r;
}

__device__ __forceinline__ bf16x8 cvt8(const float4 &a, const float4 &b) {
  int4v d = {cvtpk(a.x, a.y), cvtpk(a.z, a.w), cvtpk(b.x, b.y), cvtpk(b.z, b.w)};
  union { int4v i; bf16x8 h; } u;
  u.i = d;
  return u.h;
}

// tanh(s + bias) with bias pre-folded: c2 = C1*bias
__device__ __forceinline__ float tanh_fold(float s, float c2) {
  float e  = __builtin_amdgcn_exp2f(__builtin_fmaf(s, C1, c2));
  float rc = __builtin_amdgcn_rcpf(e + 1.0f);
  return __builtin_fmaf(-2.0f, rc, 1.0f);
}

// Raw workgroup barrier: orders LDS writes (lgkmcnt) but leaves global x
// prefetch loads (vmcnt) in flight — critical at 1 block/CU, where a
// __syncthreads vmcnt(0) drain would serialize HBM latency into every step
// (no co-resident block to cover it).  sched_barrier(0) is mandatory: LLVM's
// s_barrier is NOT a memory fence and will hoist post-barrier ds_reads
// (round-9 NaN lesson).  This exact bar() passed validation in round 8.
__device__ __forceinline__ void bar() {
  asm volatile("s_waitcnt lgkmcnt(0)" ::: "memory");
  __builtin_amdgcn_s_barrier();
  __builtin_amdgcn_sched_barrier(0);
}

// One RNN step (m-cell then p-cell).  NB=16: all 16 A-rows are distinct batch
// rows — zero MFMA duplication, and every C element is valid: lane holds
// rows 4g+r (r=0..3) at col j.  No parity machinery, no redistribution.
// m_old carried in registers (mo = n from the p-cell, validated round 12).
template<bool FIN>
__device__ __forceinline__ void step_cells(
    int arow, int g8, int j, int rowb,
    const bf16x8 &x0, const bf16x8 &x1,
    bf16x8 &mo0, bf16x8 &mo1,
    const bf16x8 (&Bm)[6], const bf16x8 (&Bp)[6],
    float c2m, float c2p, const f32x4 &Z,
    unsigned short (*sm)[72],
    unsigned short (*sp_c)[72], unsigned short (*sp_p)[72],
    float (*mfin)[68], float (*pfin)[68])
{
  // p_old fragments (used by both cells; buffer not rewritten this step)
  bf16x8 p0 = *(const bf16x8 *)&sp_p[arow][g8];
  bf16x8 p1 = *(const bf16x8 *)&sp_p[arow][32 + g8];

  // ---------------- metrics cell: in = [x | p_old | m_old(carried)]
  {
    f32x4 a0 = MFMA16(x0, Bm[0], Z);
    f32x4 a1 = MFMA16(x1, Bm[1], Z);
    a0 = MFMA16(p0, Bm[2], a0);
    a1 = MFMA16(p1, Bm[3], a1);
    a0 = MFMA16(mo0, Bm[4], a0);
    a1 = MFMA16(mo1, Bm[5], a1);
#pragma unroll
    for (int r = 0; r < 4; ++r) {
      float tv = tanh_fold(a0[r] + a1[r], c2m);
      sm[rowb + r][j] = rhu(tv);
      if (FIN) mfin[rowb + r][j] = tv;
    }
  }
  bar();   // m_new visible to all waves
  // ---------------- price cell: in = [x | m_new | p_old]
  {
    bf16x8 n0 = *(const bf16x8 *)&sm[arow][g8];
    bf16x8 n1 = *(const bf16x8 *)&sm[arow][32 + g8];
    f32x4 b0 = MFMA16(x0, Bp[0], Z);
    f32x4 b1 = MFMA16(x1, Bp[1], Z);
    b0 = MFMA16(n0, Bp[2], b0);
    b1 = MFMA16(n1, Bp[3], b1);
    b0 = MFMA16(p0, Bp[4], b0);
    b1 = MFMA16(p1, Bp[5], b1);
#pragma unroll
    for (int r = 0; r < 4; ++r) {
      float tv = tanh_fold(b0[r] + b1[r], c2p);
      sp_c[rowb + r][j] = rhu(tv);
      if (FIN) pfin[rowb + r][j] = tv;
    }
    mo0 = n0;   // carry m(t) -> next step's m_old
    mo1 = n1;
  }
  bar();   // p_new visible; prev p-buffer free next step
}

__global__ __launch_bounds__(256, 1)
void mr_rnn_kernel(const float *__restrict__ x,
                   const float *__restrict__ mWih, const float *__restrict__ mWhh,
                   const float *__restrict__ mbih, const float *__restrict__ mbhh,
                   const float *__restrict__ pWih, const float *__restrict__ pWhh,
                   const float *__restrict__ pbih, const float *__restrict__ pbhh,
                   const float *__restrict__ plW,  const float *__restrict__ plb,
                   const float *__restrict__ mlW,  const float *__restrict__ mlb,
                   float *__restrict__ out, int B)
{
  __shared__ __align__(16) unsigned short sm[NB][72];      // single m buffer
  __shared__ __align__(16) unsigned short sp[2][NB][72];   // p double buffer
  __shared__ __align__(16) float s_mfin[NB][68], s_pfin[NB][68];

  const int tid  = threadIdx.x;
  const int lane = tid & 63;
  const int q    = tid >> 6;        // wave id -> output col tile
  const int l15  = lane & 15;
  const int arow = l15;             // batch row within block (all 16 distinct)
  const int g    = lane >> 4;       // k-group
  const int j    = q * 16 + l15;    // output feature owned by this lane's wave
  const int b0   = blockIdx.x * NB;
  const int g8   = g * 8;
  const int rowb = g * 4;           // C rows 4g..4g+3 owned by this lane

  // ---- register-resident bf16 weight B-fragments: B[k][j] = W[j][k]
  bf16x8 Bm[6], Bp[6];
#pragma unroll
  for (int kt = 0; kt < 6; ++kt) {
    const int k0 = kt * 32 + g8;
#pragma unroll
    for (int i = 0; i < 8; ++i) {
      const int k = k0 + i;
      float wm = (k < 128) ? mWih[j * 128 + k] : mWhh[j * 64 + (k - 128)];
      float wp = (k < 128) ? pWih[j * 128 + k] : pWhh[j * 64 + (k - 128)];
      Bm[kt][i] = (short)brne(wm);
      Bp[kt][i] = (short)brne(wp);
    }
  }
  const float c2m = C1 * (mbih[j] + mbhh[j]);   // bias folded into exp2 arg
  const float c2p = C1 * (pbih[j] + pbhh[j]);
  const f32x4 Z = {0.f, 0.f, 0.f, 0.f};         // hoisted accumulator seed

  // ---- zero the t=-1 p-state buffer (parity index 1); m(-1)=0 is carried
  for (int idx = tid; idx < NB * 72; idx += 256) {
    const int bb = idx / 72, kk = idx % 72;
    sp[1][bb][kk] = 0;
  }
  bf16x8 mo0 = {0, 0, 0, 0, 0, 0, 0, 0};   // m(-1) = 0 (bf16 zero bits)
  bf16x8 mo1 = {0, 0, 0, 0, 0, 0, 0, 0};

  // ---- x stream: lane covers batch b0+arow, features [g8,g8+8) and
  //      [32+g8,32+g8+8), EVERY step.  2-deep named-register prefetch (Q/R).
  const float *pxl = x + (size_t)(b0 + arow) * T_LEN * F_DIM + g8;
  float4 Q0 = *(const float4 *)(pxl);
  float4 Q1 = *(const float4 *)(pxl + 4);
  float4 Q2 = *(const float4 *)(pxl + 32);
  float4 Q3 = *(const float4 *)(pxl + 36);
  bf16x8 x0 = cvt8(Q0, Q1);
  bf16x8 x1 = cvt8(Q2, Q3);
  float4 R0 = *(const float4 *)(pxl + F_DIM);
  float4 R1 = *(const float4 *)(pxl + F_DIM + 4);
  float4 R2 = *(const float4 *)(pxl + F_DIM + 32);
  float4 R3 = *(const float4 *)(pxl + F_DIM + 36);
  __syncthreads();   // zero-init visible (one full drain, outside the loop)

  // invariant at loop top: x0/x1 = x(t) converted, R = raw x(t+1)
#pragma unroll 1
  for (int t = 0; t < T_LEN - 2; t += 2) {
    // prefetch raw x(t+2) into Q (stays in flight across bar()s)
    Q0 = *(const float4 *)(pxl + 2 * F_DIM);
    Q1 = *(const float4 *)(pxl + 2 * F_DIM + 4);
    Q2 = *(const float4 *)(pxl + 2 * F_DIM + 32);
    Q3 = *(const float4 *)(pxl + 2 * F_DIM + 36);
    // step t (even): p cur parity 0, prev 1
    step_cells<false>(arow, g8, j, rowb, x0, x1, mo0, mo1,
                      Bm, Bp, c2m, c2p, Z,
                      sm, sp[0], sp[1], s_mfin, s_pfin);
    x0 = cvt8(R0, R1);   // x(t+1)
    x1 = cvt8(R2, R3);
    // prefetch raw x(t+3) into R
    R0 = *(const float4 *)(pxl + 3 * F_DIM);
    R1 = *(const float4 *)(pxl + 3 * F_DIM + 4);
    R2 = *(const float4 *)(pxl + 3 * F_DIM + 32);
    R3 = *(const float4 *)(pxl + 3 * F_DIM + 36);
    // step t+1 (odd): p cur parity 1, prev 0
    step_cells<false>(arow, g8, j, rowb, x0, x1, mo0, mo1,
                      Bm, Bp, c2m, c2p, Z,
                      sm, sp[1], sp[0], s_mfin, s_pfin);
    x0 = cvt8(Q0, Q1);   // x(t+2)
    x1 = cvt8(Q2, Q3);
    pxl += 2 * F_DIM;
  }
  // ---- tail: steps 510, 511 (x0=x(510), R=raw x(511); 511 writes finals)
  step_cells<false>(arow, g8, j, rowb, x0, x1, mo0, mo1,
                    Bm, Bp, c2m, c2p, Z,
                    sm, sp[0], sp[1], s_mfin, s_pfin);
  x0 = cvt8(R0, R1);
  x1 = cvt8(R2, R3);
  step_cells<true>(arow, g8, j, rowb, x0, x1, mo0, mo1,
                   Bm, Bp, c2m, c2p, Z,
                   sm, sp[1], sp[0], s_mfin, s_pfin);
  __syncthreads();   // finals visible to head threads (full drain, once)

  // ---- heads
  if (tid < NB) {
    const int b = tid;
    float acc = plb[0];
#pragma unroll 1
    for (int k = 0; k < 64; ++k) acc += s_pfin[b][k] * plW[k];
    out[b0 + b] = acc;
  } else if (tid < NB + NB * 8) {
    const int r = tid - NB;
    const int b = r >> 3, e = r & 7;
    float acc = mlb[e];
#pragma unroll 1
    for (int k = 0; k < 64; ++k) acc += s_mfin[b][k] * mlW[e * 64 + k];
    out[(size_t)B + (size_t)(b0 + b) * 8 + e] = acc;
  }
}

extern "C" void kernel_launch(void* const* d_in, const int* in_sizes, int n_in,
                              void* d_out, int out_size, void* d_ws, size_t ws_size,
                              hipStream_t stream) {
  (void)n_in; (void)out_size; (void)d_ws; (void)ws_size;
  const float* x    = (const float*)d_in[0];
  const float* mWih = (const float*)d_in[1];
  const float* mWhh = (const float*)d_in[2];
  const float* mbih = (const float*)d_in[3];
  const float* mbhh = (const float*)d_in[4];
  const float* pWih = (const float*)d_in[5];
  const float* pWhh = (const float*)d_in[6];
  const float* pbih = (const float*)d_in[7];
  const float* pbhh = (const float*)d_in[8];
  const float* plW  = (const float*)d_in[9];
  const float* plb  = (const float*)d_in[10];
  const float* mlW  = (const float*)d_in[11];
  const float* mlb  = (const float*)d_in[12];
  const int B = in_sizes[0] / (T_LEN * F_DIM);
  const int nblk = B / NB;   // 256 blocks -> 1 block/CU, 16 valid rows/MFMA
  mr_rnn_kernel<<<dim3(nblk), dim3(256), 0, stream>>>(
      x, mWih, mWhh, mbih, mbhh, pWih, pWhh, pbih, pbhh,
      plW, plb, mlW, mlb, (float*)d_out, B);
}